// Round 3
// baseline (1023.390 us; speedup 1.0000x reference)
//
#include <hip/hip_runtime.h>

// VQ-VAE quantizer: x [B=32, C=64, T=4096] f32, emb [K=1024, D=64] f32.
// Outputs flat f32: quant_out [B*C*T], codebook_loss [1], commitment_loss [1],
// idx [B*T] (written as float).
//
// CORRECTNESS-CRITICAL (validated in R2, absmax 3.8e-6 = zero argmin flips):
// the checker recomputes the reference with numpy in f32. d = (S+e2[k])-2*dot
// has magnitude ~64, so d is quantized to ulp(64)=7.6e-6 while top-2 gaps are
// ~3e-5 -> ties at the min are common and the argmin is decided by numpy's
// exact rounding. We replicate it bit-for-bit:
//   S     = numpy pairwise_sum(x*x), n=64: 8 accumulators stride-8, then
//           ((r0+r1)+(r2+r3))+((r4+r5)+(r6+r7)); mul and add separately rounded.
//   e2[k] = same pairwise pattern.
//   dot   = sequential-k single-accumulator FMA chain (BLAS sgemm order).
//   d     = fl(fl(S + e2[k]) - fl(2*dot))   [contract(off)]
//   argmin: strict <, ascending k; cross-thread merge via packed u64
//           (bits(d)<<10 | k): d>0 so bit order == value order, low bits k
//           reproduce numpy first-index tie-break.
// DO NOT change the dot/S/combine arithmetic or ordering.
//
// R3 perf change: K-split x4 (4 threads/row, 256 candidates each) to fix
// occupancy 23% / VALUBusy 54% / VGPR 44 (xr not register-resident).

#define KCB 1024
#define DD 64
#define BB 32
#define TT 4096
#define BT (BB * TT)            // 131072 rows
#define NELEM (BB * DD * TT)    // 8388608

#define KSPLIT 4
#define KPER (KCB / KSPLIT)     // 256 candidates per thread
#define ROWS_PER_BLOCK 64

#define WS_LOSS 0
#define WS_E2 64

__global__ void vq_init_ws(float* ws) {
    if (threadIdx.x == 0 && blockIdx.x == 0) ws[WS_LOSS] = 0.0f;
}

// e2[k] = numpy pairwise sum of fl(e_i*e_i), n=64
__global__ void vq_compute_e2(const float* __restrict__ emb, float* __restrict__ ws) {
#pragma clang fp contract(off)
    int k = blockIdx.x * blockDim.x + threadIdx.x;
    if (k < KCB) {
        const float* e = emb + (size_t)k * DD;
        float r[8];
#pragma unroll
        for (int j = 0; j < 8; ++j) r[j] = e[j] * e[j];
#pragma unroll
        for (int i = 8; i < 64; i += 8) {
#pragma unroll
            for (int j = 0; j < 8; ++j) r[j] += e[i + j] * e[i + j];
        }
        ws[WS_E2 + k] = ((r[0] + r[1]) + (r[2] + r[3])) + ((r[4] + r[5]) + (r[6] + r[7]));
    }
}

__launch_bounds__(256, 4)
__global__ void vq_main(const float* __restrict__ x, const float* __restrict__ emb,
                        float* __restrict__ out, float* __restrict__ ws) {
#pragma clang fp contract(off)
    const int tid = threadIdx.x;
    const int lane = tid & 63;       // row-within-block
    const int ks = tid >> 6;         // k-slice 0..3 (one wave per slice)

    const int row = blockIdx.x * ROWS_PER_BLOCK + lane;  // 0..BT-1
    const int b = row >> 12;         // / TT
    const int t = row & (TT - 1);    // % TT

    __shared__ unsigned long long redu[ROWS_PER_BLOCK];
    __shared__ float bsum;
    if (tid < ROWS_PER_BLOCK) redu[tid] = ~0ull;
    if (tid == 0) bsum = 0.0f;
    __syncthreads();

    // Row's x vector (stride TT per channel; coalesced across lanes).
    const float* xp = x + (size_t)b * DD * TT + t;
    float xr[DD];
#pragma unroll
    for (int c = 0; c < DD; ++c) xr[c] = xp[(size_t)c * TT];

    // S = numpy pairwise sum of fl(x_i*x_i), n=64
    float r[8];
#pragma unroll
    for (int j = 0; j < 8; ++j) r[j] = xr[j] * xr[j];
#pragma unroll
    for (int i = 8; i < 64; i += 8) {
#pragma unroll
        for (int j = 0; j < 8; ++j) r[j] += xr[i + j] * xr[i + j];
    }
    const float S = ((r[0] + r[1]) + (r[2] + r[3])) + ((r[4] + r[5]) + (r[6] + r[7]));

    const float* e2 = ws + WS_E2;

    float best = 3.4e38f;
    int bidx = 0;

    // This thread's candidate slice [k0, k0+KPER). k is wave-uniform (wave ==
    // one slice) -> emb/e2 loads are scalar. 4 sequential FMA chains in
    // flight for ILP; each chain bit-matches the BLAS dot.
    const int k0 = ks * KPER;
    for (int kk = 0; kk < KPER; kk += 4) {
        const int k = k0 + kk;
        const float* ep = emb + (size_t)k * DD;
        float d0 = 0.f, d1 = 0.f, d2 = 0.f, d3 = 0.f;
#pragma unroll
        for (int i = 0; i < DD; ++i) {
            d0 = __builtin_fmaf(ep[i],          xr[i], d0);
            d1 = __builtin_fmaf(ep[DD + i],     xr[i], d1);
            d2 = __builtin_fmaf(ep[2 * DD + i], xr[i], d2);
            d3 = __builtin_fmaf(ep[3 * DD + i], xr[i], d3);
        }
        float t0 = S + e2[k + 0]; float s0 = t0 - 2.0f * d0;
        float t1 = S + e2[k + 1]; float s1 = t1 - 2.0f * d1;
        float t2 = S + e2[k + 2]; float s2 = t2 - 2.0f * d2;
        float t3 = S + e2[k + 3]; float s3 = t3 - 2.0f * d3;
        if (s0 < best) { best = s0; bidx = k + 0; }
        if (s1 < best) { best = s1; bidx = k + 1; }
        if (s2 < best) { best = s2; bidx = k + 2; }
        if (s3 < best) { best = s3; bidx = k + 3; }
    }

    // Merge the 4 slices: packed (bits(d)<<10 | k); d>0 => bit-monotone.
    unsigned long long packed =
        ((unsigned long long)__float_as_uint(best) << 10) | (unsigned int)bidx;
    atomicMin(&redu[lane], packed);
    __syncthreads();

    const int fidx = (int)(redu[lane] & 1023u);

    // Epilogue split 4 ways: thread handles dims [ks*16, ks*16+16).
    const float4* eq = (const float4*)(emb + (size_t)fidx * DD + ks * 16);
    float* oq = out + (size_t)b * DD * TT + t + (size_t)(ks * 16) * TT;
    float lsum = 0.f;
#pragma unroll
    for (int c4 = 0; c4 < 4; ++c4) {
        float4 v = eq[c4];
        oq[(size_t)(4 * c4 + 0) * TT] = v.x;
        oq[(size_t)(4 * c4 + 1) * TT] = v.y;
        oq[(size_t)(4 * c4 + 2) * TT] = v.z;
        oq[(size_t)(4 * c4 + 3) * TT] = v.w;
        float a0 = v.x - xr[ks * 16 + 4 * c4 + 0];
        float a1 = v.y - xr[ks * 16 + 4 * c4 + 1];
        float a2 = v.z - xr[ks * 16 + 4 * c4 + 2];
        float a3 = v.w - xr[ks * 16 + 4 * c4 + 3];
        lsum = __builtin_fmaf(a0, a0, lsum);
        lsum = __builtin_fmaf(a1, a1, lsum);
        lsum = __builtin_fmaf(a2, a2, lsum);
        lsum = __builtin_fmaf(a3, a3, lsum);
    }

    if (ks == 0) out[NELEM + 2 + row] = (float)fidx;

    // wave(64) shuffle reduction, LDS-stage, one global atomic per block
#pragma unroll
    for (int off = 32; off > 0; off >>= 1) lsum += __shfl_down(lsum, off);
    if (lane == 0) atomicAdd(&bsum, lsum);
    __syncthreads();
    if (tid == 0) atomicAdd(ws + WS_LOSS, bsum);
}

__global__ void vq_finalize(const float* __restrict__ ws, float* __restrict__ out) {
    if (threadIdx.x == 0 && blockIdx.x == 0) {
        float M = ws[WS_LOSS] / (float)NELEM;
        out[NELEM + 0] = M;           // codebook_loss
        out[NELEM + 1] = 0.25f * M;   // commitment_loss = BETA * same mean
    }
}

extern "C" void kernel_launch(void* const* d_in, const int* in_sizes, int n_in,
                              void* d_out, int out_size, void* d_ws, size_t ws_size,
                              hipStream_t stream) {
    const float* x = (const float*)d_in[0];
    const float* emb = (const float*)d_in[1];
    float* out = (float*)d_out;
    float* ws = (float*)d_ws;

    vq_init_ws<<<1, 64, 0, stream>>>(ws);
    vq_compute_e2<<<KCB / 256, 256, 0, stream>>>(emb, ws);
    vq_main<<<BT / ROWS_PER_BLOCK, 256, 0, stream>>>(x, emb, out, ws);
    vq_finalize<<<1, 64, 0, stream>>>(ws, out);
}

// Round 4
// 418.464 us; speedup vs baseline: 2.4456x; 2.4456x over previous
//
#include <hip/hip_runtime.h>

// VQ-VAE quantizer: x [B=32, C=64, T=4096] f32, emb [K=1024, D=64] f32.
// Outputs flat f32: quant_out [B*C*T], codebook_loss [1], commitment_loss [1],
// idx [B*T] (written as float).
//
// CORRECTNESS-CRITICAL (validated R2/R3, absmax 3.8e-6 = zero argmin flips):
// the checker recomputes the reference with numpy in f32. d = (S+e2[k])-2*dot
// is ~64 so it is quantized at ulp(64)=7.6e-6; many rows have top-2 gaps below
// that -> argmin decided by numpy's exact rounding. Replicated bit-for-bit:
//   S, e2[k]: numpy pairwise_sum of fl(v*v), n=64 (8 accs stride-8, then
//             ((r0+r1)+(r2+r3))+((r4+r5)+(r6+r7)); mul/add separately rounded)
//   dot     : sequential-k single-accumulator FMA chain (BLAS order)
//   d       : fl(fl(S + e2[k]) - fl(2*dot))   [contract(off)]
//   argmin  : strict <, ascending k; cross-thread merge via packed u64
//             (bits(d)<<10 | k) — d>0 so bit order == value order.
// DO NOT change the dot/S/combine arithmetic or ordering. DO NOT split D.
//
// Perf history:
//   R2: 1 thread/row, 453us. VGPR=44 -> compiler REMATERIALIZED x loads inside
//       k-loop (1 L1 load per FMA). 4x over the 109us VALU-FMA floor.
//   R3: K-split x4, 1017us. Two bugs: (a) epilogue xr[ks*16+..] dynamic index
//       -> xr demoted to scratch (WRITE_SIZE +131MB = 256B x 524288 threads);
//       (b) ks=tid>>6 not provably uniform -> emb loads became VMEM (SGPR 32).
//   R4: keep K-split x4; readfirstlane(ks) -> scalar emb loads; asm-pin xr[]
//       to force register residency; epilogue uses wave-uniform branches with
//       constant xr indices.

#define KCB 1024
#define DD 64
#define BB 32
#define TT 4096
#define BT (BB * TT)            // 131072 rows
#define NELEM (BB * DD * TT)    // 8388608

#define KSPLIT 4
#define KPER (KCB / KSPLIT)     // 256 candidates per thread
#define ROWS_PER_BLOCK 64

#define WS_LOSS 0
#define WS_E2 64

__global__ void vq_init_ws(float* ws) {
    if (threadIdx.x == 0 && blockIdx.x == 0) ws[WS_LOSS] = 0.0f;
}

// e2[k] = numpy pairwise sum of fl(e_i*e_i), n=64
__global__ void vq_compute_e2(const float* __restrict__ emb, float* __restrict__ ws) {
#pragma clang fp contract(off)
    int k = blockIdx.x * blockDim.x + threadIdx.x;
    if (k < KCB) {
        const float* e = emb + (size_t)k * DD;
        float r[8];
#pragma unroll
        for (int j = 0; j < 8; ++j) r[j] = e[j] * e[j];
#pragma unroll
        for (int i = 8; i < 64; i += 8) {
#pragma unroll
            for (int j = 0; j < 8; ++j) r[j] += e[i + j] * e[i + j];
        }
        ws[WS_E2 + k] = ((r[0] + r[1]) + (r[2] + r[3])) + ((r[4] + r[5]) + (r[6] + r[7]));
    }
}

__launch_bounds__(256, 4)
__global__ void vq_main(const float* __restrict__ x, const float* __restrict__ emb,
                        float* __restrict__ out, float* __restrict__ ws) {
#pragma clang fp contract(off)
    const int tid = threadIdx.x;
    const int lane = tid & 63;                                   // row-within-block
    const int ks = __builtin_amdgcn_readfirstlane(tid >> 6);     // k-slice, SGPR

    const int row = blockIdx.x * ROWS_PER_BLOCK + lane;  // 0..BT-1
    const int b = row >> 12;         // / TT
    const int t = row & (TT - 1);    // % TT

    __shared__ unsigned long long redu[ROWS_PER_BLOCK];
    __shared__ float bsum;
    if (tid < ROWS_PER_BLOCK) redu[tid] = ~0ull;
    if (tid == 0) bsum = 0.0f;
    __syncthreads();

    // Row's x vector (stride TT per channel; coalesced across lanes).
    const float* xp = x + (size_t)b * DD * TT + t;
    float xr[DD];
#pragma unroll
    for (int c = 0; c < DD; ++c) xr[c] = xp[(size_t)c * TT];
    // Pin each element into a VGPR: opaque defs cannot be rematerialized as
    // reloads (R2's pathology) and cannot be demoted to scratch as an array.
#pragma unroll
    for (int c = 0; c < DD; ++c) asm volatile("" : "+v"(xr[c]));

    // S = numpy pairwise sum of fl(x_i*x_i), n=64
    float r[8];
#pragma unroll
    for (int j = 0; j < 8; ++j) r[j] = xr[j] * xr[j];
#pragma unroll
    for (int i = 8; i < 64; i += 8) {
#pragma unroll
        for (int j = 0; j < 8; ++j) r[j] += xr[i + j] * xr[i + j];
    }
    const float S = ((r[0] + r[1]) + (r[2] + r[3])) + ((r[4] + r[5]) + (r[6] + r[7]));

    const float* e2 = ws + WS_E2;

    float best = 3.4e38f;
    int bidx = 0;

    // Candidate slice [k0, k0+KPER). k is uniform (SGPR ks) -> emb/e2 loads
    // are s_loads, broadcast free into v_fmac. 4 sequential chains for ILP;
    // each chain bit-matches the BLAS dot.
    const int k0 = ks * KPER;
    for (int kk = 0; kk < KPER; kk += 4) {
        const int k = k0 + kk;
        const float* ep = emb + (size_t)k * DD;
        float d0 = 0.f, d1 = 0.f, d2 = 0.f, d3 = 0.f;
#pragma unroll
        for (int i = 0; i < DD; ++i) {
            d0 = __builtin_fmaf(ep[i],          xr[i], d0);
            d1 = __builtin_fmaf(ep[DD + i],     xr[i], d1);
            d2 = __builtin_fmaf(ep[2 * DD + i], xr[i], d2);
            d3 = __builtin_fmaf(ep[3 * DD + i], xr[i], d3);
        }
        float t0 = S + e2[k + 0]; float s0 = t0 - 2.0f * d0;
        float t1 = S + e2[k + 1]; float s1 = t1 - 2.0f * d1;
        float t2 = S + e2[k + 2]; float s2 = t2 - 2.0f * d2;
        float t3 = S + e2[k + 3]; float s3 = t3 - 2.0f * d3;
        if (s0 < best) { best = s0; bidx = k + 0; }
        if (s1 < best) { best = s1; bidx = k + 1; }
        if (s2 < best) { best = s2; bidx = k + 2; }
        if (s3 < best) { best = s3; bidx = k + 3; }
    }

    // Merge the 4 slices: packed (bits(d)<<10 | k); d>0 => bit-monotone;
    // low bits k give numpy first-index tie-break.
    unsigned long long packed =
        ((unsigned long long)__float_as_uint(best) << 10) | (unsigned int)bidx;
    atomicMin(&redu[lane], packed);
    __syncthreads();

    const int fidx = (int)(redu[lane] & 1023u);

    // Epilogue: 4-way dim split via WAVE-UNIFORM branches (ks is SGPR), all
    // xr accesses constant-indexed. q = emb[fidx]; quant_out == q; loss
    // accumulates (q-x)^2; idx written as float by slice 0.
    const float* eql = emb + (size_t)fidx * DD;
    float* oq = out + (size_t)b * DD * TT + t;
    float lsum = 0.f;
#pragma unroll
    for (int c4 = 0; c4 < DD / 4; ++c4) {
        if (ks == (c4 >> 2)) {   // uniform: s_cmp + s_cbranch, no divergence
            float4 v = *(const float4*)(eql + 4 * c4);
            oq[(size_t)(4 * c4 + 0) * TT] = v.x;
            oq[(size_t)(4 * c4 + 1) * TT] = v.y;
            oq[(size_t)(4 * c4 + 2) * TT] = v.z;
            oq[(size_t)(4 * c4 + 3) * TT] = v.w;
            float a0 = v.x - xr[4 * c4 + 0];
            float a1 = v.y - xr[4 * c4 + 1];
            float a2 = v.z - xr[4 * c4 + 2];
            float a3 = v.w - xr[4 * c4 + 3];
            lsum = __builtin_fmaf(a0, a0, lsum);
            lsum = __builtin_fmaf(a1, a1, lsum);
            lsum = __builtin_fmaf(a2, a2, lsum);
            lsum = __builtin_fmaf(a3, a3, lsum);
        }
    }

    if (ks == 0) out[NELEM + 2 + row] = (float)fidx;

    // wave(64) shuffle reduction, LDS-stage, one global atomic per block
#pragma unroll
    for (int off = 32; off > 0; off >>= 1) lsum += __shfl_down(lsum, off);
    if (lane == 0) atomicAdd(&bsum, lsum);
    __syncthreads();
    if (tid == 0) atomicAdd(ws + WS_LOSS, bsum);
}

__global__ void vq_finalize(const float* __restrict__ ws, float* __restrict__ out) {
    if (threadIdx.x == 0 && blockIdx.x == 0) {
        float M = ws[WS_LOSS] / (float)NELEM;
        out[NELEM + 0] = M;           // codebook_loss
        out[NELEM + 1] = 0.25f * M;   // commitment_loss = BETA * same mean
    }
}

extern "C" void kernel_launch(void* const* d_in, const int* in_sizes, int n_in,
                              void* d_out, int out_size, void* d_ws, size_t ws_size,
                              hipStream_t stream) {
    const float* x = (const float*)d_in[0];
    const float* emb = (const float*)d_in[1];
    float* out = (float*)d_out;
    float* ws = (float*)d_ws;

    vq_init_ws<<<1, 64, 0, stream>>>(ws);
    vq_compute_e2<<<KCB / 256, 256, 0, stream>>>(emb, ws);
    vq_main<<<BT / ROWS_PER_BLOCK, 256, 0, stream>>>(x, emb, out, ws);
    vq_finalize<<<1, 64, 0, stream>>>(ws, out);
}